// Round 19
// baseline (801.991 us; speedup 1.0000x reference)
//
#include <hip/hip_runtime.h>
#include <math.h>

typedef unsigned short u16;
typedef unsigned int u32;
typedef __bf16 bf16x8 __attribute__((ext_vector_type(8)));
typedef float f32x4 __attribute__((ext_vector_type(4)));
typedef u16 us8 __attribute__((ext_vector_type(8)));
typedef u16 us4 __attribute__((ext_vector_type(4)));

#define TOKENS 1024
#define DIM 256
#define SEQ 512

// ---------- helpers ----------

__device__ __forceinline__ u16 f2bf(float f) {
  u32 x = __float_as_uint(f);
  x += 0x7fffu + ((x >> 16) & 1u);
  return (u16)(x >> 16);
}

// silu + 8 cubic B-spline bases, uniform extended grid g[j] = (j-3)*0.4f - 1.0f.
// Compile-time-reciprocal Cox-de Boor (denominators constant).
__device__ __forceinline__ void expand9(float x, u16* sil, us8* u) {
  float sig = 1.0f / (1.0f + expf(-x));
  *sil = f2bf(x * sig);
  float bs[11];
#pragma unroll
  for (int j = 0; j < 11; j++) {
    float gj  = (float)(j - 3) * 0.4f - 1.0f;
    float gj1 = (float)(j - 2) * 0.4f - 1.0f;
    bs[j] = (x >= gj && x < gj1) ? 1.0f : 0.0f;
  }
#pragma unroll
  for (int k = 1; k <= 3; k++) {
#pragma unroll
    for (int j = 0; j < 10; j++) {
      if (j + k < 11) {
        float gj   = (float)(j - 3) * 0.4f - 1.0f;
        float gj1  = (float)(j - 2) * 0.4f - 1.0f;
        float gjk  = (float)(j + k - 3) * 0.4f - 1.0f;
        float gjk1 = (float)(j + k - 2) * 0.4f - 1.0f;
        float linv = 1.0f / (gjk - gj);
        float rinv = 1.0f / (gjk1 - gj1);
        bs[j] = (x - gj) * linv * bs[j] + (gjk1 - x) * rinv * bs[j + 1];
      }
    }
  }
#pragma unroll
  for (int c = 0; c < 8; c++) (*u)[c] = f2bf(bs[c]);
}

// 256-thread block sum (4 waves of 64)
__device__ __forceinline__ float block_sum_256(float v) {
  __shared__ float red[4];
  int t = threadIdx.x, lane = t & 63, wid = t >> 6;
#pragma unroll
  for (int o = 32; o > 0; o >>= 1) v += __shfl_down(v, o, 64);
  __syncthreads();
  if (lane == 0) red[wid] = v;
  __syncthreads();
  return red[0] + red[1] + red[2] + red[3];
}

// 64-lane butterfly sum (all lanes get total)
__device__ __forceinline__ float wave_sum_64(float v) {
#pragma unroll
  for (int o = 32; o > 0; o >>= 1) v += __shfl_xor(v, o, 64);
  return v;
}

// ---------- embedding + LN (eps 1e-12) + expand ----------

__global__ void embed_ln_x(const int* __restrict__ ids, const float* __restrict__ wemb,
                           const float* __restrict__ tt, const float* __restrict__ pe,
                           const float* __restrict__ g, const float* __restrict__ bta,
                           float* __restrict__ xout, u16* __restrict__ Xe) {
  int row = blockIdx.x, t = threadIdx.x;
  int id = ids[row];
  float v = wemb[(size_t)id * DIM + t] + tt[DIM + t] + pe[DIM + t];
  float mu = block_sum_256(v) * (1.0f / 256.0f);
  float d = v - mu;
  float var = block_sum_256(d * d) * (1.0f / 256.0f);
  float y = d * rsqrtf(var + 1e-12f) * g[t] + bta[t];
  xout[(size_t)row * DIM + t] = y;
  size_t base = (size_t)row * 2304;
  u16 s; us8 u;
  expand9(y, &s, &u);
  Xe[base + t] = s;
  *(us8*)(Xe + base + 256 + (size_t)t * 8) = u;
}

// ---------- (sum of nsum partials) [+gelu] [+res] + LN + expand ----------
// 4 rows/block, one 64-lane wave per row; float4 loads; butterfly reductions.

__global__ void add_ln_x(const float* __restrict__ a, int nsum, int sstride,
                         const float* __restrict__ res,
                         const float* __restrict__ g, const float* __restrict__ bta,
                         float eps, int dogelu,
                         float* __restrict__ xout, u16* __restrict__ Xe) {
  int t = threadIdx.x;
  int row = blockIdx.x * 4 + (t >> 6);
  int lane = t & 63;
  int col = lane * 4;
  int idx = row * 256 + col;
  float4 v = *(const float4*)(a + idx);
  for (int s = 1; s < nsum; s++) {
    float4 p = *(const float4*)(a + (size_t)s * sstride + idx);
    v.x += p.x; v.y += p.y; v.z += p.z; v.w += p.w;
  }
  if (dogelu) {
    const float kk = 0.70710678118654752f;
    v.x = 0.5f * v.x * (1.0f + erff(v.x * kk));
    v.y = 0.5f * v.y * (1.0f + erff(v.y * kk));
    v.z = 0.5f * v.z * (1.0f + erff(v.z * kk));
    v.w = 0.5f * v.w * (1.0f + erff(v.w * kk));
  }
  if (res) {
    float4 rr = *(const float4*)(res + idx);
    v.x += rr.x; v.y += rr.y; v.z += rr.z; v.w += rr.w;
  }
  float mu = wave_sum_64(v.x + v.y + v.z + v.w) * (1.0f / 256.0f);
  float4 d;
  d.x = v.x - mu; d.y = v.y - mu; d.z = v.z - mu; d.w = v.w - mu;
  float var = wave_sum_64(d.x * d.x + d.y * d.y + d.z * d.z + d.w * d.w) * (1.0f / 256.0f);
  float rs = rsqrtf(var + eps);
  float4 y;
  y.x = d.x * rs; y.y = d.y * rs; y.z = d.z * rs; y.w = d.w * rs;
  if (g) {
    float4 gv = *(const float4*)(g + col);
    float4 bv = *(const float4*)(bta + col);
    y.x = y.x * gv.x + bv.x; y.y = y.y * gv.y + bv.y;
    y.z = y.z * gv.z + bv.z; y.w = y.w * gv.w + bv.w;
  }
  *(float4*)(xout + idx) = y;
  size_t base = (size_t)row * 2304;
  u16 s0_, s1_, s2_, s3_;
  us8 u0, u1, u2, u3;
  expand9(y.x, &s0_, &u0);
  expand9(y.y, &s1_, &u1);
  expand9(y.z, &s2_, &u2);
  expand9(y.w, &s3_, &u3);
  us4 sil4; sil4[0] = s0_; sil4[1] = s1_; sil4[2] = s2_; sil4[3] = s3_;
  *(us4*)(Xe + base + col) = sil4;
  *(us8*)(Xe + base + 256 + (size_t)col * 8) = u0;
  *(us8*)(Xe + base + 256 + (size_t)(col + 1) * 8) = u1;
  *(us8*)(Xe + base + 256 + (size_t)(col + 2) * 8) = u2;
  *(us8*)(Xe + base + 256 + (size_t)(col + 3) * 8) = u3;
}

// ---------- sum 3 f1 partials + relu + expand: f1p[3][1024*1024] -> Xe2[1024,9216] ----------

__global__ void expand_ff(const float* __restrict__ X, u16* __restrict__ Xe) {
  int i4 = (blockIdx.x * 256 + threadIdx.x) * 4;
  int n = i4 >> 10, i = i4 & 1023;
  const size_t str = (size_t)TOKENS * 1024;
  float4 v = *(const float4*)(X + i4);
  float4 p1 = *(const float4*)(X + str + i4);
  float4 p2 = *(const float4*)(X + 2 * str + i4);
  v.x = fmaxf(v.x + p1.x + p2.x, 0.0f);
  v.y = fmaxf(v.y + p1.y + p2.y, 0.0f);
  v.z = fmaxf(v.z + p1.z + p2.z, 0.0f);
  v.w = fmaxf(v.w + p1.w + p2.w, 0.0f);
  size_t base = (size_t)n * 9216;
  u16 s0_, s1_, s2_, s3_;
  us8 u0, u1, u2, u3;
  expand9(v.x, &s0_, &u0);
  expand9(v.y, &s1_, &u1);
  expand9(v.z, &s2_, &u2);
  expand9(v.w, &s3_, &u3);
  us4 sil4; sil4[0] = s0_; sil4[1] = s1_; sil4[2] = s2_; sil4[3] = s3_;
  *(us4*)(Xe + base + i) = sil4;
  *(us8*)(Xe + base + 1024 + (size_t)i * 8) = u0;
  *(us8*)(Xe + base + 1024 + (size_t)(i + 1) * 8) = u1;
  *(us8*)(Xe + base + 1024 + (size_t)(i + 2) * 8) = u2;
  *(us8*)(Xe + base + 1024 + (size_t)(i + 3) * 8) = u3;
}

// ---------- GEMM: C[1024,N] = A[1024,K](bf16) @ Wvirt[N,K]^T, W = [base|spline] f32 ----------
// f32 weights converted RNE->bf16 during staging. XCD-contiguous remap, XOR-swizzled
// DOUBLE-BUFFERED LDS with ONE barrier per K-step: ST tile(k+1)->buf[p^1] (regs from
// last iter, latency hidden) -> issue LD tile(k+2) -> MFMA buf[p] -> barrier -> p^=1.
// Zero extra VGPRs vs single-buffer (the levers that paid VGPRs all regressed).
// blockIdx.z = K-split slice (kchunk, multiple of BK); partial C at z*TOKENS*N.
// EPI: 0 = f32 store; 1 = relu+KAN-expand into XeOut.

#define LDA4(c, v) { int r_ = (c) * RPC + (t >> LGP); int g_ = t & (GPB - 1); \
    v = *(const uint4*)(A + (size_t)(m0 + r_) * K + k0n + g_ * 8); }
#define LDB4(c, va, vb) { int r_ = (c) * RPC + (t >> LGP); int g_ = t & (GPB - 1); \
    int kv_ = k0n + g_ * 8; \
    const float* p_ = (kv_ < infeat) ? (Wb + (size_t)(onb + r_) * infeat + kv_) \
                                     : (Ws + (size_t)(onb + r_) * infeat * 8 + (kv_ - infeat)); \
    va = *(const float4*)p_; vb = *(const float4*)(p_ + 4); }
#define STA4(dst, c, v) { int r_ = (c) * RPC + (t >> LGP); int g_ = t & (GPB - 1); \
    *(uint4*)(&(dst)[r_ * BK + ((g_ ^ (r_ & (GPB - 1))) << 3)]) = v; }
#define STB4(dst, c, va, vb) { int r_ = (c) * RPC + (t >> LGP); int g_ = t & (GPB - 1); \
    bf16x8 h_; \
    h_[0] = (__bf16)va.x; h_[1] = (__bf16)va.y; h_[2] = (__bf16)va.z; h_[3] = (__bf16)va.w; \
    h_[4] = (__bf16)vb.x; h_[5] = (__bf16)vb.y; h_[6] = (__bf16)vb.z; h_[7] = (__bf16)vb.w; \
    *(bf16x8*)(&(dst)[r_ * BK + ((g_ ^ (r_ & (GPB - 1))) << 3)]) = h_; }

#define LOAD_ALL { LDA4(0, pa0); LDA4(1, pa1); LDA4(2, pa2); LDA4(3, pa3); \
    LDB4(0, pb0a, pb0b); LDB4(1, pb1a, pb1b); LDB4(2, pb2a, pb2b); LDB4(3, pb3a, pb3b); }
#define STORE_ALL(ad, bd) { STA4(ad, 0, pa0); STA4(ad, 1, pa1); STA4(ad, 2, pa2); STA4(ad, 3, pa3); \
    STB4(bd, 0, pb0a, pb0b); STB4(bd, 1, pb1a, pb1b); STB4(bd, 2, pb2a, pb2b); STB4(bd, 3, pb3a, pb3b); }

template <int BM, int BN, int BK, int MINW, int EPI>
__global__ __launch_bounds__(256, MINW)
void gemm_kw(const u16* __restrict__ A,
             const float* __restrict__ b0, const float* __restrict__ s0,
             const float* __restrict__ b1, const float* __restrict__ s1,
             const float* __restrict__ b2, const float* __restrict__ s2,
             int nper, int N, int K, int infeat, int kchunk, float* __restrict__ C,
             u16* __restrict__ XeOut, int infOut) {
  constexpr int GPB = BK / 8;
  constexpr int LGP = (GPB == 8) ? 3 : 4;
  constexpr int RPC = 256 / GPB;
  static_assert(BM / RPC == 4 && BN / RPC == 4, "need exactly 4+4 chunks");
  constexpr int FM = BM / 32, FN = BN / 32;
  __shared__ u16 As[2][BM * BK];
  __shared__ u16 Bs[2][BN * BK];
  const int gx = gridDim.x;
  const int nwg = gx * gridDim.y;
  int g = blockIdx.y * gx + blockIdx.x;
  int lin = g;
  if ((nwg & 7) == 0) lin = (g & 7) * (nwg >> 3) + (g >> 3);
  const int m0 = (lin % gx) * BM;
  const int n0 = (lin / gx) * BN;
  const int z = blockIdx.z;
  const int kbeg = z * kchunk;
  const int kend = (kbeg + kchunk < K) ? kbeg + kchunk : K;
  const int t = threadIdx.x;
  const int lane = t & 63, wid = t >> 6;
  const int wm = (wid >> 1) * (BM / 2), wn = (wid & 1) * (BN / 2);
  const int proj = n0 / nper;
  const float* Wb = proj == 0 ? b0 : (proj == 1 ? b1 : b2);
  const float* Ws = proj == 0 ? s0 : (proj == 1 ? s1 : s2);
  const int onb = n0 - proj * nper;

  f32x4 acc[FM][FN];
#pragma unroll
  for (int i = 0; i < FM; i++)
#pragma unroll
    for (int j = 0; j < FN; j++) acc[i][j] = (f32x4){0.f, 0.f, 0.f, 0.f};

  const int frow = lane & 15;
  const int cgrp = lane >> 4;

  uint4 pa0, pa1, pa2, pa3;
  float4 pb0a, pb0b, pb1a, pb1b, pb2a, pb2b, pb3a, pb3b;
  const int nk = (kend - kbeg) / BK;          // exact: all call sites BK-multiples
  int k0n = kbeg;
  LOAD_ALL;                                   // tile 0
  STORE_ALL(As[0], Bs[0]);                    // buf0 <- tile 0
  if (nk > 1) { k0n = kbeg + BK; LOAD_ALL; }  // issue tile 1
  __syncthreads();                            // buf0 ready

  int p = 0;
  for (int ki = 0; ki < nk; ki++) {
    if (ki + 1 < nk) {
      u16* an = &As[p ^ 1][0];
      u16* bn = &Bs[p ^ 1][0];
      STORE_ALL(an, bn);                      // buf[p^1] <- tile ki+1 (regs from last iter)
      if (ki + 2 < nk) { k0n = kbeg + (ki + 2) * BK; LOAD_ALL; }  // issue tile ki+2
    }
    const u16* ac = &As[p][0];
    const u16* bc = &Bs[p][0];
#pragma unroll
    for (int kk = 0; kk < BK; kk += 32) {
      bf16x8 af[FM], bfr[FN];
#pragma unroll
      for (int i = 0; i < FM; i++) {
        int rr = wm + i * 16 + frow;
        int ch = (kk >> 3) + cgrp;
        af[i] = *reinterpret_cast<const bf16x8*>(&ac[rr * BK + ((ch ^ (rr & (GPB - 1))) << 3)]);
      }
#pragma unroll
      for (int j = 0; j < FN; j++) {
        int rr = wn + j * 16 + frow;
        int ch = (kk >> 3) + cgrp;
        bfr[j] = *reinterpret_cast<const bf16x8*>(&bc[rr * BK + ((ch ^ (rr & (GPB - 1))) << 3)]);
      }
#pragma unroll
      for (int i = 0; i < FM; i++)
#pragma unroll
        for (int j = 0; j < FN; j++)
          acc[i][j] = __builtin_amdgcn_mfma_f32_16x16x32_bf16(af[i], bfr[j], acc[i][j], 0, 0, 0);
    }
    __syncthreads();                          // buf[p^1] ready; all done reading buf[p]
    p ^= 1;
  }

  const int crow = (lane >> 4) * 4;
  const int ccol = lane & 15;
  if constexpr (EPI == 0) {
    float* Cz = C + (size_t)z * TOKENS * N;
#pragma unroll
    for (int i = 0; i < FM; i++)
#pragma unroll
      for (int j = 0; j < FN; j++) {
        int row = m0 + wm + i * 16 + crow;
        int col = n0 + wn + j * 16 + ccol;
#pragma unroll
        for (int r = 0; r < 4; r++)
          Cz[(size_t)(row + r) * N + col] = acc[i][j][r];
      }
  } else {
    const int ldXe = infOut * 9;
#pragma unroll
    for (int i = 0; i < FM; i++)
#pragma unroll
      for (int j = 0; j < FN; j++) {
        int row0 = m0 + wm + i * 16 + crow;
        int col = n0 + wn + j * 16 + ccol;
#pragma unroll
        for (int r = 0; r < 4; r++) {
          float y = fmaxf(acc[i][j][r], 0.0f);
          u16 s; us8 u;
          expand9(y, &s, &u);
          size_t base = (size_t)(row0 + r) * ldXe;
          XeOut[base + col] = s;
          *(us8*)(XeOut + base + infOut + (size_t)col * 8) = u;
        }
      }
  }
}

// ---------- fused attention: QK^T + softmax + PV + KAN-expand ----------
// qkv provided as 3 split-K partials (summed at load, float4-vectorized staging);
// 32-row K/V tiles with register prefetch (half the barriers, loads overlap compute).

__global__ void attn_fused(const float* __restrict__ qkv, u16* __restrict__ Xe) {
  const float* q1 = qkv + (size_t)TOKENS * 768;
  const float* q2 = qkv + (size_t)2 * TOKENS * 768;
  int bh = blockIdx.x, b = bh >> 2, h = bh & 3;
  int s0 = blockIdx.y * 16;
  int t = threadIdx.x;
  __shared__ float Qs[16][68];
  __shared__ float Ks[32][68];
  __shared__ float Ss[16][513];
  __shared__ float red[16][17];
  __shared__ float Vs[32][68];
  const int srow = t >> 4, sd0 = (t & 15) * 4;
  {
    int rr = t >> 4, d0 = (t & 15) * 4;
    size_t ix = (size_t)(b * SEQ + s0 + rr) * 768 + h * 64 + d0;
    float4 v0 = *(const float4*)(qkv + ix);
    float4 v1 = *(const float4*)(q1 + ix);
    float4 v2 = *(const float4*)(q2 + ix);
    float4 o;
    o.x = v0.x + v1.x + v2.x; o.y = v0.y + v1.y + v2.y;
    o.z = v0.z + v1.z + v2.z; o.w = v0.w + v1.w + v2.w;
    *(float4*)&Qs[rr][d0] = o;
  }
  int r = t >> 4, cc = t & 15;

#define LD32(dst0, dst1, kc, off) { \
    size_t ixa_ = (size_t)(b * SEQ + (kc) + srow) * 768 + (off) + h * 64 + sd0; \
    size_t ixb_ = ixa_ + (size_t)16 * 768; \
    float4 a0_ = *(const float4*)(qkv + ixa_); \
    float4 a1_ = *(const float4*)(q1 + ixa_); \
    float4 a2_ = *(const float4*)(q2 + ixa_); \
    dst0.x = a0_.x + a1_.x + a2_.x; dst0.y = a0_.y + a1_.y + a2_.y; \
    dst0.z = a0_.z + a1_.z + a2_.z; dst0.w = a0_.w + a1_.w + a2_.w; \
    float4 b0_ = *(const float4*)(qkv + ixb_); \
    float4 b1_ = *(const float4*)(q1 + ixb_); \
    float4 b2_ = *(const float4*)(q2 + ixb_); \
    dst1.x = b0_.x + b1_.x + b2_.x; dst1.y = b0_.y + b1_.y + b2_.y; \
    dst1.z = b0_.z + b1_.z + b2_.z; dst1.w = b0_.w + b1_.w + b2_.w; }

  float4 rk0, rk1;
  LD32(rk0, rk1, 0, 256);
  for (int tile = 0; tile < 16; tile++) {
    *(float4*)&Ks[srow][sd0] = rk0;
    *(float4*)&Ks[16 + srow][sd0] = rk1;
    __syncthreads();
    if (tile < 15) LD32(rk0, rk1, (tile + 1) * 32, 256);
    int colbase = tile * 32;
#pragma unroll
    for (int c2 = 0; c2 < 2; c2++) {
      int col = cc + c2 * 16;
      float acc = 0.f;
#pragma unroll
      for (int d4 = 0; d4 < 16; d4++) {
        float4 qv = *(const float4*)&Qs[r][d4 * 4];
        float4 kv = *(const float4*)&Ks[col][d4 * 4];
        acc += qv.x * kv.x;
        acc += qv.y * kv.y;
        acc += qv.z * kv.z;
        acc += qv.w * kv.w;
      }
      Ss[r][colbase + col] = acc * 0.125f;
    }
    __syncthreads();
  }
  float mx = -3.4e38f;
  for (int j = cc; j < SEQ; j += 16) mx = fmaxf(mx, Ss[r][j]);
  red[r][cc] = mx;
  __syncthreads();
  if (cc == 0) {
    float m = red[r][0];
#pragma unroll
    for (int j = 1; j < 16; j++) m = fmaxf(m, red[r][j]);
    red[r][16] = m;
  }
  __syncthreads();
  mx = red[r][16];
  float sm = 0.f;
  for (int j = cc; j < SEQ; j += 16) {
    float e = expf(Ss[r][j] - mx);
    Ss[r][j] = e;
    sm += e;
  }
  __syncthreads();
  red[r][cc] = sm;
  __syncthreads();
  if (cc == 0) {
    float s = 0.f;
#pragma unroll
    for (int j = 0; j < 16; j++) s += red[r][j];
    red[r][16] = s;
  }
  __syncthreads();
  float inv = 1.0f / red[r][16];
  for (int j = cc; j < SEQ; j += 16) Ss[r][j] *= inv;
  int dd = cc * 4;
  float a0 = 0.f, a1 = 0.f, a2 = 0.f, a3 = 0.f;
  float4 rv0, rv1;
  LD32(rv0, rv1, 0, 512);
  for (int tile = 0; tile < 16; tile++) {
    *(float4*)&Vs[srow][sd0] = rv0;
    *(float4*)&Vs[16 + srow][sd0] = rv1;
    __syncthreads();
    if (tile < 15) LD32(rv0, rv1, (tile + 1) * 32, 512);
    int kc = tile * 32;
#pragma unroll
    for (int kk = 0; kk < 32; kk++) {
      float p = Ss[r][kc + kk];
      float4 vv = *(const float4*)&Vs[kk][dd];
      a0 += p * vv.x;
      a1 += p * vv.y;
      a2 += p * vv.z;
      a3 += p * vv.w;
    }
    __syncthreads();
  }
#undef LD32
  int row = b * SEQ + s0 + r;
  size_t base = (size_t)row * 2304;
  float av[4] = {a0, a1, a2, a3};
#pragma unroll
  for (int j = 0; j < 4; j++) {
    int col = h * 64 + dd + j;
    u16 s; us8 u;
    expand9(av[j], &s, &u);
    Xe[base + col] = s;
    *(us8*)(Xe + base + 256 + (size_t)col * 8) = u;
  }
}

// ---------- launch ----------

extern "C" void kernel_launch(void* const* d_in, const int* in_sizes, int n_in,
                              void* d_out, int out_size, void* d_ws, size_t ws_size,
                              hipStream_t stream) {
  const int* ids = (const int*)d_in[0];
  const float* wemb = (const float*)d_in[1];
  const float* ttemb = (const float*)d_in[2];
  const float* pemb = (const float*)d_in[3];
  const float* elg = (const float*)d_in[4];
  const float* elb = (const float*)d_in[5];
  const float* qb = (const float*)d_in[6], *qs = (const float*)d_in[7];
  const float* kb = (const float*)d_in[8], *ks = (const float*)d_in[9];
  const float* vb = (const float*)d_in[10], *vs = (const float*)d_in[11];
  const float* ob = (const float*)d_in[12], *osp = (const float*)d_in[13];
  const float* f1b = (const float*)d_in[14], *f1s = (const float*)d_in[15];
  const float* f2b = (const float*)d_in[16], *f2s = (const float*)d_in[17];
  const float* l1g = (const float*)d_in[18], *l1b = (const float*)d_in[19];
  const float* l2g = (const float*)d_in[20], *l2b = (const float*)d_in[21];
  const float* hkb = (const float*)d_in[22], *hks = (const float*)d_in[23];
  const float* hob = (const float*)d_in[24], *hos = (const float*)d_in[25];
  float* out = (float*)d_out;

  char* w = (char*)d_ws;
  const size_t MB = 1 << 20;
  float* xbuf = (float*)(w);                 // 1 MB  [1024*256]
  float* tmp  = (float*)(w + 1 * MB);        // 1 MB  (head LN scratch)
  float* qkv  = (float*)(w + 2 * MB);        // 9 MB  [3][1024*768]  split-K partials
  float* part = (float*)(w + 11 * MB);       // 9 MB  [9][1024*256]  split-K partials
  u16*   Xe2  = (u16*)  (w + 20 * MB);       // 18 MB [1024*9216]    f1-out expansion
  u16*   Xe   = (u16*)  (w + 38 * MB);       // 4.5MB [1024*2304]
  float* f1p  = (float*)(w + 43 * MB);       // 12 MB [3][1024*1024] f1 split-K partials

  embed_ln_x<<<TOKENS, 256, 0, stream>>>(ids, wemb, ttemb, pemb, elg, elb, xbuf, Xe);

  for (int l = 0; l < 4; l++) {
    const float* qbl = qb + (size_t)l * 65536, *qsl = qs + (size_t)l * 524288;
    const float* kbl = kb + (size_t)l * 65536, *ksl = ks + (size_t)l * 524288;
    const float* vbl = vb + (size_t)l * 65536, *vsl = vs + (size_t)l * 524288;
    const float* obl = ob + (size_t)l * 65536, *osl = osp + (size_t)l * 524288;
    const float* f1bl = f1b + (size_t)l * 262144, *f1sl = f1s + (size_t)l * 2097152;
    const float* f2bl = f2b + (size_t)l * 262144, *f2sl = f2s + (size_t)l * 2097152;

    // qkv: split-K x3 (576 blocks, 6 iters/slice)
    gemm_kw<64, 64, 128, 2, 0><<<dim3(16, 12, 3), 256, 0, stream>>>(
        Xe, qbl, qsl, kbl, ksl, vbl, vsl, 256, 768, 2304, 256, 768, qkv, nullptr, 0);
    attn_fused<<<dim3(8, 32), 256, 0, stream>>>(qkv, Xe);
    // o-proj: split-K x9 (576 blocks, 2 iters/slice)
    gemm_kw<64, 64, 128, 2, 0><<<dim3(16, 4, 9), 256, 0, stream>>>(
        Xe, obl, osl, obl, osl, obl, osl, 256, 256, 2304, 256, 256, part, nullptr, 0);
    add_ln_x<<<TOKENS / 4, 256, 0, stream>>>(part, 9, TOKENS * 256, xbuf,
                                             l1g + l * 256, l1b + l * 256, 1e-5f, 0, xbuf, Xe);
    // f1: split-K x3 (768 blocks, 6 iters/slice); expand_ff sums + relu + expands
    gemm_kw<64, 64, 128, 2, 0><<<dim3(16, 16, 3), 256, 0, stream>>>(
        Xe, f1bl, f1sl, f1bl, f1sl, f1bl, f1sl, 1024, 1024, 2304, 256, 768,
        f1p, nullptr, 0);
    expand_ff<<<1024, 256, 0, stream>>>(f1p, Xe2);
    // f2: split-K x8 (512 blocks, 9 iters/slice)
    gemm_kw<64, 64, 128, 2, 0><<<dim3(16, 4, 8), 256, 0, stream>>>(
        Xe2, f2bl, f2sl, f2bl, f2sl, f2bl, f2sl, 256, 256, 9216, 1024, 1152,
        part, nullptr, 0);
    add_ln_x<<<TOKENS / 4, 256, 0, stream>>>(part, 8, TOKENS * 256, xbuf,
                                             l2g + l * 256, l2b + l * 256, 1e-5f, 0, xbuf, Xe);
  }

  // head: KAN -> gelu -> LN(no affine, eps 1e-12) -> KAN to vocab
  gemm_kw<64, 64, 128, 2, 0><<<dim3(16, 4, 9), 256, 0, stream>>>(
      Xe, hkb, hks, hkb, hks, hkb, hks, 256, 256, 2304, 256, 256, part, nullptr, 0);
  add_ln_x<<<TOKENS / 4, 256, 0, stream>>>(part, 9, TOKENS * 256, nullptr, nullptr, nullptr,
                                           1e-12f, 1, tmp, Xe);
  gemm_kw<128, 128, 64, 1, 0><<<dim3(8, 250), 256, 0, stream>>>(
      Xe, hob, hos, hob, hos, hob, hos, 32000, 32000, 2304, 256, 2304, out, nullptr, 0);
}

// Round 20
// 780.276 us; speedup vs baseline: 1.0278x; 1.0278x over previous
//
#include <hip/hip_runtime.h>
#include <math.h>

typedef unsigned short u16;
typedef unsigned int u32;
typedef __bf16 bf16x8 __attribute__((ext_vector_type(8)));
typedef float f32x4 __attribute__((ext_vector_type(4)));
typedef u16 us8 __attribute__((ext_vector_type(8)));
typedef u16 us4 __attribute__((ext_vector_type(4)));

#define TOKENS 1024
#define DIM 256
#define SEQ 512

// ---------- helpers ----------

__device__ __forceinline__ u16 f2bf(float f) {
  u32 x = __float_as_uint(f);
  x += 0x7fffu + ((x >> 16) & 1u);
  return (u16)(x >> 16);
}

// silu + 8 cubic B-spline bases, uniform extended grid g[j] = (j-3)*0.4f - 1.0f.
// Compile-time-reciprocal Cox-de Boor (denominators constant).
__device__ __forceinline__ void expand9(float x, u16* sil, us8* u) {
  float sig = 1.0f / (1.0f + expf(-x));
  *sil = f2bf(x * sig);
  float bs[11];
#pragma unroll
  for (int j = 0; j < 11; j++) {
    float gj  = (float)(j - 3) * 0.4f - 1.0f;
    float gj1 = (float)(j - 2) * 0.4f - 1.0f;
    bs[j] = (x >= gj && x < gj1) ? 1.0f : 0.0f;
  }
#pragma unroll
  for (int k = 1; k <= 3; k++) {
#pragma unroll
    for (int j = 0; j < 10; j++) {
      if (j + k < 11) {
        float gj   = (float)(j - 3) * 0.4f - 1.0f;
        float gj1  = (float)(j - 2) * 0.4f - 1.0f;
        float gjk  = (float)(j + k - 3) * 0.4f - 1.0f;
        float gjk1 = (float)(j + k - 2) * 0.4f - 1.0f;
        float linv = 1.0f / (gjk - gj);
        float rinv = 1.0f / (gjk1 - gj1);
        bs[j] = (x - gj) * linv * bs[j] + (gjk1 - x) * rinv * bs[j + 1];
      }
    }
  }
#pragma unroll
  for (int c = 0; c < 8; c++) (*u)[c] = f2bf(bs[c]);
}

// 256-thread block sum (4 waves of 64)
__device__ __forceinline__ float block_sum_256(float v) {
  __shared__ float red[4];
  int t = threadIdx.x, lane = t & 63, wid = t >> 6;
#pragma unroll
  for (int o = 32; o > 0; o >>= 1) v += __shfl_down(v, o, 64);
  __syncthreads();
  if (lane == 0) red[wid] = v;
  __syncthreads();
  return red[0] + red[1] + red[2] + red[3];
}

// 64-lane butterfly sum (all lanes get total)
__device__ __forceinline__ float wave_sum_64(float v) {
#pragma unroll
  for (int o = 32; o > 0; o >>= 1) v += __shfl_xor(v, o, 64);
  return v;
}

// ---------- embedding + LN (eps 1e-12) + expand ----------

__global__ void embed_ln_x(const int* __restrict__ ids, const float* __restrict__ wemb,
                           const float* __restrict__ tt, const float* __restrict__ pe,
                           const float* __restrict__ g, const float* __restrict__ bta,
                           float* __restrict__ xout, u16* __restrict__ Xe) {
  int row = blockIdx.x, t = threadIdx.x;
  int id = ids[row];
  float v = wemb[(size_t)id * DIM + t] + tt[DIM + t] + pe[DIM + t];
  float mu = block_sum_256(v) * (1.0f / 256.0f);
  float d = v - mu;
  float var = block_sum_256(d * d) * (1.0f / 256.0f);
  float y = d * rsqrtf(var + 1e-12f) * g[t] + bta[t];
  xout[(size_t)row * DIM + t] = y;
  size_t base = (size_t)row * 2304;
  u16 s; us8 u;
  expand9(y, &s, &u);
  Xe[base + t] = s;
  *(us8*)(Xe + base + 256 + (size_t)t * 8) = u;
}

// ---------- (sum of nsum partials) [+gelu] [+res] + LN + expand ----------
// 4 rows/block, one 64-lane wave per row; float4 loads; butterfly reductions.

__global__ void add_ln_x(const float* __restrict__ a, int nsum, int sstride,
                         const float* __restrict__ res,
                         const float* __restrict__ g, const float* __restrict__ bta,
                         float eps, int dogelu,
                         float* __restrict__ xout, u16* __restrict__ Xe) {
  int t = threadIdx.x;
  int row = blockIdx.x * 4 + (t >> 6);
  int lane = t & 63;
  int col = lane * 4;
  int idx = row * 256 + col;
  float4 v = *(const float4*)(a + idx);
  for (int s = 1; s < nsum; s++) {
    float4 p = *(const float4*)(a + (size_t)s * sstride + idx);
    v.x += p.x; v.y += p.y; v.z += p.z; v.w += p.w;
  }
  if (dogelu) {
    const float kk = 0.70710678118654752f;
    v.x = 0.5f * v.x * (1.0f + erff(v.x * kk));
    v.y = 0.5f * v.y * (1.0f + erff(v.y * kk));
    v.z = 0.5f * v.z * (1.0f + erff(v.z * kk));
    v.w = 0.5f * v.w * (1.0f + erff(v.w * kk));
  }
  if (res) {
    float4 rr = *(const float4*)(res + idx);
    v.x += rr.x; v.y += rr.y; v.z += rr.z; v.w += rr.w;
  }
  float mu = wave_sum_64(v.x + v.y + v.z + v.w) * (1.0f / 256.0f);
  float4 d;
  d.x = v.x - mu; d.y = v.y - mu; d.z = v.z - mu; d.w = v.w - mu;
  float var = wave_sum_64(d.x * d.x + d.y * d.y + d.z * d.z + d.w * d.w) * (1.0f / 256.0f);
  float rs = rsqrtf(var + eps);
  float4 y;
  y.x = d.x * rs; y.y = d.y * rs; y.z = d.z * rs; y.w = d.w * rs;
  if (g) {
    float4 gv = *(const float4*)(g + col);
    float4 bv = *(const float4*)(bta + col);
    y.x = y.x * gv.x + bv.x; y.y = y.y * gv.y + bv.y;
    y.z = y.z * gv.z + bv.z; y.w = y.w * gv.w + bv.w;
  }
  *(float4*)(xout + idx) = y;
  size_t base = (size_t)row * 2304;
  u16 s0_, s1_, s2_, s3_;
  us8 u0, u1, u2, u3;
  expand9(y.x, &s0_, &u0);
  expand9(y.y, &s1_, &u1);
  expand9(y.z, &s2_, &u2);
  expand9(y.w, &s3_, &u3);
  us4 sil4; sil4[0] = s0_; sil4[1] = s1_; sil4[2] = s2_; sil4[3] = s3_;
  *(us4*)(Xe + base + col) = sil4;
  *(us8*)(Xe + base + 256 + (size_t)col * 8) = u0;
  *(us8*)(Xe + base + 256 + (size_t)(col + 1) * 8) = u1;
  *(us8*)(Xe + base + 256 + (size_t)(col + 2) * 8) = u2;
  *(us8*)(Xe + base + 256 + (size_t)(col + 3) * 8) = u3;
}

// ---------- sum 3 f1 partials + relu + expand: f1p[3][1024*1024] -> Xe2[1024,9216] ----------

__global__ void expand_ff(const float* __restrict__ X, u16* __restrict__ Xe) {
  int i4 = (blockIdx.x * 256 + threadIdx.x) * 4;
  int n = i4 >> 10, i = i4 & 1023;
  const size_t str = (size_t)TOKENS * 1024;
  float4 v = *(const float4*)(X + i4);
  float4 p1 = *(const float4*)(X + str + i4);
  float4 p2 = *(const float4*)(X + 2 * str + i4);
  v.x = fmaxf(v.x + p1.x + p2.x, 0.0f);
  v.y = fmaxf(v.y + p1.y + p2.y, 0.0f);
  v.z = fmaxf(v.z + p1.z + p2.z, 0.0f);
  v.w = fmaxf(v.w + p1.w + p2.w, 0.0f);
  size_t base = (size_t)n * 9216;
  u16 s0_, s1_, s2_, s3_;
  us8 u0, u1, u2, u3;
  expand9(v.x, &s0_, &u0);
  expand9(v.y, &s1_, &u1);
  expand9(v.z, &s2_, &u2);
  expand9(v.w, &s3_, &u3);
  us4 sil4; sil4[0] = s0_; sil4[1] = s1_; sil4[2] = s2_; sil4[3] = s3_;
  *(us4*)(Xe + base + i) = sil4;
  *(us8*)(Xe + base + 1024 + (size_t)i * 8) = u0;
  *(us8*)(Xe + base + 1024 + (size_t)(i + 1) * 8) = u1;
  *(us8*)(Xe + base + 1024 + (size_t)(i + 2) * 8) = u2;
  *(us8*)(Xe + base + 1024 + (size_t)(i + 3) * 8) = u3;
}

// ---------- GEMM: C[1024,N] = A[1024,K](bf16) @ Wvirt[N,K]^T, W = [base|spline] f32 ----------
// f32 weights converted RNE->bf16 during staging. XCD-contiguous remap, XOR-swizzled
// LDS, named-register prefetch pipeline. Single-buffer 2-barrier loop: the measured
// optimum (2-deep regs, 8-wave, global_load_lds, and LDS double-buffer all regressed:
// occupancy / L2-locality / VALU balance). blockIdx.z = K-split slice (kchunk, multiple
// of BK); partial C at z*TOKENS*N. EPI: 0 = f32 store; 1 = relu+KAN-expand into XeOut.

#define LDA4(c, v) { int r_ = (c) * RPC + (t >> LGP); int g_ = t & (GPB - 1); \
    v = *(const uint4*)(A + (size_t)(m0 + r_) * K + k0n + g_ * 8); }
#define LDB4(c, va, vb) { int r_ = (c) * RPC + (t >> LGP); int g_ = t & (GPB - 1); \
    int kv_ = k0n + g_ * 8; \
    const float* p_ = (kv_ < infeat) ? (Wb + (size_t)(onb + r_) * infeat + kv_) \
                                     : (Ws + (size_t)(onb + r_) * infeat * 8 + (kv_ - infeat)); \
    va = *(const float4*)p_; vb = *(const float4*)(p_ + 4); }
#define STA4(c, v) { int r_ = (c) * RPC + (t >> LGP); int g_ = t & (GPB - 1); \
    *(uint4*)(&As[r_ * BK + ((g_ ^ (r_ & (GPB - 1))) << 3)]) = v; }
#define STB4(c, va, vb) { int r_ = (c) * RPC + (t >> LGP); int g_ = t & (GPB - 1); \
    bf16x8 h_; \
    h_[0] = (__bf16)va.x; h_[1] = (__bf16)va.y; h_[2] = (__bf16)va.z; h_[3] = (__bf16)va.w; \
    h_[4] = (__bf16)vb.x; h_[5] = (__bf16)vb.y; h_[6] = (__bf16)vb.z; h_[7] = (__bf16)vb.w; \
    *(bf16x8*)(&Bs[r_ * BK + ((g_ ^ (r_ & (GPB - 1))) << 3)]) = h_; }

template <int BM, int BN, int BK, int MINW, int EPI>
__global__ __launch_bounds__(256, MINW)
void gemm_kw(const u16* __restrict__ A,
             const float* __restrict__ b0, const float* __restrict__ s0,
             const float* __restrict__ b1, const float* __restrict__ s1,
             const float* __restrict__ b2, const float* __restrict__ s2,
             int nper, int N, int K, int infeat, int kchunk, float* __restrict__ C,
             u16* __restrict__ XeOut, int infOut) {
  constexpr int GPB = BK / 8;
  constexpr int LGP = (GPB == 8) ? 3 : 4;
  constexpr int RPC = 256 / GPB;
  static_assert(BM / RPC == 4 && BN / RPC == 4, "need exactly 4+4 chunks");
  constexpr int FM = BM / 32, FN = BN / 32;
  __shared__ u16 As[BM * BK];
  __shared__ u16 Bs[BN * BK];
  const int gx = gridDim.x;
  const int nwg = gx * gridDim.y;
  int g = blockIdx.y * gx + blockIdx.x;
  int lin = g;
  if ((nwg & 7) == 0) lin = (g & 7) * (nwg >> 3) + (g >> 3);
  const int m0 = (lin % gx) * BM;
  const int n0 = (lin / gx) * BN;
  const int z = blockIdx.z;
  const int kbeg = z * kchunk;
  const int kend = (kbeg + kchunk < K) ? kbeg + kchunk : K;
  const int t = threadIdx.x;
  const int lane = t & 63, wid = t >> 6;
  const int wm = (wid >> 1) * (BM / 2), wn = (wid & 1) * (BN / 2);
  const int proj = n0 / nper;
  const float* Wb = proj == 0 ? b0 : (proj == 1 ? b1 : b2);
  const float* Ws = proj == 0 ? s0 : (proj == 1 ? s1 : s2);
  const int onb = n0 - proj * nper;

  f32x4 acc[FM][FN];
#pragma unroll
  for (int i = 0; i < FM; i++)
#pragma unroll
    for (int j = 0; j < FN; j++) acc[i][j] = (f32x4){0.f, 0.f, 0.f, 0.f};

  const int frow = lane & 15;
  const int cgrp = lane >> 4;

  uint4 pa0, pa1, pa2, pa3;
  float4 pb0a, pb0b, pb1a, pb1b, pb2a, pb2b, pb3a, pb3b;
  int k0n = kbeg;
  LDA4(0, pa0); LDA4(1, pa1); LDA4(2, pa2); LDA4(3, pa3);
  LDB4(0, pb0a, pb0b); LDB4(1, pb1a, pb1b); LDB4(2, pb2a, pb2b); LDB4(3, pb3a, pb3b);

  for (int k0 = kbeg; k0 < kend; k0 += BK) {
    STA4(0, pa0); STA4(1, pa1); STA4(2, pa2); STA4(3, pa3);
    STB4(0, pb0a, pb0b); STB4(1, pb1a, pb1b); STB4(2, pb2a, pb2b); STB4(3, pb3a, pb3b);
    __syncthreads();
    if (k0 + BK < kend) {                     // prefetch next tile into named registers
      k0n = k0 + BK;
      LDA4(0, pa0); LDA4(1, pa1); LDA4(2, pa2); LDA4(3, pa3);
      LDB4(0, pb0a, pb0b); LDB4(1, pb1a, pb1b); LDB4(2, pb2a, pb2b); LDB4(3, pb3a, pb3b);
    }
#pragma unroll
    for (int kk = 0; kk < BK; kk += 32) {
      bf16x8 af[FM], bfr[FN];
#pragma unroll
      for (int i = 0; i < FM; i++) {
        int rr = wm + i * 16 + frow;
        int ch = (kk >> 3) + cgrp;
        af[i] = *reinterpret_cast<const bf16x8*>(&As[rr * BK + ((ch ^ (rr & (GPB - 1))) << 3)]);
      }
#pragma unroll
      for (int j = 0; j < FN; j++) {
        int rr = wn + j * 16 + frow;
        int ch = (kk >> 3) + cgrp;
        bfr[j] = *reinterpret_cast<const bf16x8*>(&Bs[rr * BK + ((ch ^ (rr & (GPB - 1))) << 3)]);
      }
#pragma unroll
      for (int i = 0; i < FM; i++)
#pragma unroll
        for (int j = 0; j < FN; j++)
          acc[i][j] = __builtin_amdgcn_mfma_f32_16x16x32_bf16(af[i], bfr[j], acc[i][j], 0, 0, 0);
    }
    __syncthreads();
  }

  const int crow = (lane >> 4) * 4;
  const int ccol = lane & 15;
  if constexpr (EPI == 0) {
    float* Cz = C + (size_t)z * TOKENS * N;
#pragma unroll
    for (int i = 0; i < FM; i++)
#pragma unroll
      for (int j = 0; j < FN; j++) {
        int row = m0 + wm + i * 16 + crow;
        int col = n0 + wn + j * 16 + ccol;
#pragma unroll
        for (int r = 0; r < 4; r++)
          Cz[(size_t)(row + r) * N + col] = acc[i][j][r];
      }
  } else {
    const int ldXe = infOut * 9;
#pragma unroll
    for (int i = 0; i < FM; i++)
#pragma unroll
      for (int j = 0; j < FN; j++) {
        int row0 = m0 + wm + i * 16 + crow;
        int col = n0 + wn + j * 16 + ccol;
#pragma unroll
        for (int r = 0; r < 4; r++) {
          float y = fmaxf(acc[i][j][r], 0.0f);
          u16 s; us8 u;
          expand9(y, &s, &u);
          size_t base = (size_t)(row0 + r) * ldXe;
          XeOut[base + col] = s;
          *(us8*)(XeOut + base + infOut + (size_t)col * 8) = u;
        }
      }
  }
}

// ---------- fused attention: QK^T + softmax + PV + KAN-expand ----------
// qkv provided as 3 split-K partials (summed at load, float4-vectorized staging);
// 32-row K/V tiles with register prefetch (half the barriers, loads overlap compute).

__global__ void attn_fused(const float* __restrict__ qkv, u16* __restrict__ Xe) {
  const float* q1 = qkv + (size_t)TOKENS * 768;
  const float* q2 = qkv + (size_t)2 * TOKENS * 768;
  int bh = blockIdx.x, b = bh >> 2, h = bh & 3;
  int s0 = blockIdx.y * 16;
  int t = threadIdx.x;
  __shared__ float Qs[16][68];
  __shared__ float Ks[32][68];
  __shared__ float Ss[16][513];
  __shared__ float red[16][17];
  __shared__ float Vs[32][68];
  const int srow = t >> 4, sd0 = (t & 15) * 4;
  {
    int rr = t >> 4, d0 = (t & 15) * 4;
    size_t ix = (size_t)(b * SEQ + s0 + rr) * 768 + h * 64 + d0;
    float4 v0 = *(const float4*)(qkv + ix);
    float4 v1 = *(const float4*)(q1 + ix);
    float4 v2 = *(const float4*)(q2 + ix);
    float4 o;
    o.x = v0.x + v1.x + v2.x; o.y = v0.y + v1.y + v2.y;
    o.z = v0.z + v1.z + v2.z; o.w = v0.w + v1.w + v2.w;
    *(float4*)&Qs[rr][d0] = o;
  }
  int r = t >> 4, cc = t & 15;

#define LD32(dst0, dst1, kc, off) { \
    size_t ixa_ = (size_t)(b * SEQ + (kc) + srow) * 768 + (off) + h * 64 + sd0; \
    size_t ixb_ = ixa_ + (size_t)16 * 768; \
    float4 a0_ = *(const float4*)(qkv + ixa_); \
    float4 a1_ = *(const float4*)(q1 + ixa_); \
    float4 a2_ = *(const float4*)(q2 + ixa_); \
    dst0.x = a0_.x + a1_.x + a2_.x; dst0.y = a0_.y + a1_.y + a2_.y; \
    dst0.z = a0_.z + a1_.z + a2_.z; dst0.w = a0_.w + a1_.w + a2_.w; \
    float4 b0_ = *(const float4*)(qkv + ixb_); \
    float4 b1_ = *(const float4*)(q1 + ixb_); \
    float4 b2_ = *(const float4*)(q2 + ixb_); \
    dst1.x = b0_.x + b1_.x + b2_.x; dst1.y = b0_.y + b1_.y + b2_.y; \
    dst1.z = b0_.z + b1_.z + b2_.z; dst1.w = b0_.w + b1_.w + b2_.w; }

  float4 rk0, rk1;
  LD32(rk0, rk1, 0, 256);
  for (int tile = 0; tile < 16; tile++) {
    *(float4*)&Ks[srow][sd0] = rk0;
    *(float4*)&Ks[16 + srow][sd0] = rk1;
    __syncthreads();
    if (tile < 15) LD32(rk0, rk1, (tile + 1) * 32, 256);
    int colbase = tile * 32;
#pragma unroll
    for (int c2 = 0; c2 < 2; c2++) {
      int col = cc + c2 * 16;
      float acc = 0.f;
#pragma unroll
      for (int d4 = 0; d4 < 16; d4++) {
        float4 qv = *(const float4*)&Qs[r][d4 * 4];
        float4 kv = *(const float4*)&Ks[col][d4 * 4];
        acc += qv.x * kv.x;
        acc += qv.y * kv.y;
        acc += qv.z * kv.z;
        acc += qv.w * kv.w;
      }
      Ss[r][colbase + col] = acc * 0.125f;
    }
    __syncthreads();
  }
  float mx = -3.4e38f;
  for (int j = cc; j < SEQ; j += 16) mx = fmaxf(mx, Ss[r][j]);
  red[r][cc] = mx;
  __syncthreads();
  if (cc == 0) {
    float m = red[r][0];
#pragma unroll
    for (int j = 1; j < 16; j++) m = fmaxf(m, red[r][j]);
    red[r][16] = m;
  }
  __syncthreads();
  mx = red[r][16];
  float sm = 0.f;
  for (int j = cc; j < SEQ; j += 16) {
    float e = expf(Ss[r][j] - mx);
    Ss[r][j] = e;
    sm += e;
  }
  __syncthreads();
  red[r][cc] = sm;
  __syncthreads();
  if (cc == 0) {
    float s = 0.f;
#pragma unroll
    for (int j = 0; j < 16; j++) s += red[r][j];
    red[r][16] = s;
  }
  __syncthreads();
  float inv = 1.0f / red[r][16];
  for (int j = cc; j < SEQ; j += 16) Ss[r][j] *= inv;
  int dd = cc * 4;
  float a0 = 0.f, a1 = 0.f, a2 = 0.f, a3 = 0.f;
  float4 rv0, rv1;
  LD32(rv0, rv1, 0, 512);
  for (int tile = 0; tile < 16; tile++) {
    *(float4*)&Vs[srow][sd0] = rv0;
    *(float4*)&Vs[16 + srow][sd0] = rv1;
    __syncthreads();
    if (tile < 15) LD32(rv0, rv1, (tile + 1) * 32, 512);
    int kc = tile * 32;
#pragma unroll
    for (int kk = 0; kk < 32; kk++) {
      float p = Ss[r][kc + kk];
      float4 vv = *(const float4*)&Vs[kk][dd];
      a0 += p * vv.x;
      a1 += p * vv.y;
      a2 += p * vv.z;
      a3 += p * vv.w;
    }
    __syncthreads();
  }
#undef LD32
  int row = b * SEQ + s0 + r;
  size_t base = (size_t)row * 2304;
  float av[4] = {a0, a1, a2, a3};
#pragma unroll
  for (int j = 0; j < 4; j++) {
    int col = h * 64 + dd + j;
    u16 s; us8 u;
    expand9(av[j], &s, &u);
    Xe[base + col] = s;
    *(us8*)(Xe + base + 256 + (size_t)col * 8) = u;
  }
}

// ---------- launch ----------

extern "C" void kernel_launch(void* const* d_in, const int* in_sizes, int n_in,
                              void* d_out, int out_size, void* d_ws, size_t ws_size,
                              hipStream_t stream) {
  const int* ids = (const int*)d_in[0];
  const float* wemb = (const float*)d_in[1];
  const float* ttemb = (const float*)d_in[2];
  const float* pemb = (const float*)d_in[3];
  const float* elg = (const float*)d_in[4];
  const float* elb = (const float*)d_in[5];
  const float* qb = (const float*)d_in[6], *qs = (const float*)d_in[7];
  const float* kb = (const float*)d_in[8], *ks = (const float*)d_in[9];
  const float* vb = (const float*)d_in[10], *vs = (const float*)d_in[11];
  const float* ob = (const float*)d_in[12], *osp = (const float*)d_in[13];
  const float* f1b = (const float*)d_in[14], *f1s = (const float*)d_in[15];
  const float* f2b = (const float*)d_in[16], *f2s = (const float*)d_in[17];
  const float* l1g = (const float*)d_in[18], *l1b = (const float*)d_in[19];
  const float* l2g = (const float*)d_in[20], *l2b = (const float*)d_in[21];
  const float* hkb = (const float*)d_in[22], *hks = (const float*)d_in[23];
  const float* hob = (const float*)d_in[24], *hos = (const float*)d_in[25];
  float* out = (float*)d_out;

  char* w = (char*)d_ws;
  const size_t MB = 1 << 20;
  float* xbuf = (float*)(w);                 // 1 MB  [1024*256]
  float* tmp  = (float*)(w + 1 * MB);        // 1 MB  (head LN scratch)
  float* qkv  = (float*)(w + 2 * MB);        // 9 MB  [3][1024*768]  split-K partials
  float* part = (float*)(w + 11 * MB);       // 9 MB  [9][1024*256]  split-K partials
  u16*   Xe2  = (u16*)  (w + 20 * MB);       // 18 MB [1024*9216]    f1-out expansion
  u16*   Xe   = (u16*)  (w + 38 * MB);       // 4.5MB [1024*2304]
  float* f1p  = (float*)(w + 43 * MB);       // 12 MB [3][1024*1024] f1 split-K partials

  embed_ln_x<<<TOKENS, 256, 0, stream>>>(ids, wemb, ttemb, pemb, elg, elb, xbuf, Xe);

  for (int l = 0; l < 4; l++) {
    const float* qbl = qb + (size_t)l * 65536, *qsl = qs + (size_t)l * 524288;
    const float* kbl = kb + (size_t)l * 65536, *ksl = ks + (size_t)l * 524288;
    const float* vbl = vb + (size_t)l * 65536, *vsl = vs + (size_t)l * 524288;
    const float* obl = ob + (size_t)l * 65536, *osl = osp + (size_t)l * 524288;
    const float* f1bl = f1b + (size_t)l * 262144, *f1sl = f1s + (size_t)l * 2097152;
    const float* f2bl = f2b + (size_t)l * 262144, *f2sl = f2s + (size_t)l * 2097152;

    // qkv: split-K x3 (576 blocks, 6 iters/slice)
    gemm_kw<64, 64, 128, 2, 0><<<dim3(16, 12, 3), 256, 0, stream>>>(
        Xe, qbl, qsl, kbl, ksl, vbl, vsl, 256, 768, 2304, 256, 768, qkv, nullptr, 0);
    attn_fused<<<dim3(8, 32), 256, 0, stream>>>(qkv, Xe);
    // o-proj: split-K x9 (576 blocks, 2 iters/slice)
    gemm_kw<64, 64, 128, 2, 0><<<dim3(16, 4, 9), 256, 0, stream>>>(
        Xe, obl, osl, obl, osl, obl, osl, 256, 256, 2304, 256, 256, part, nullptr, 0);
    add_ln_x<<<TOKENS / 4, 256, 0, stream>>>(part, 9, TOKENS * 256, xbuf,
                                             l1g + l * 256, l1b + l * 256, 1e-5f, 0, xbuf, Xe);
    // f1: split-K x3 (768 blocks, 6 iters/slice); expand_ff sums + relu + expands
    gemm_kw<64, 64, 128, 2, 0><<<dim3(16, 16, 3), 256, 0, stream>>>(
        Xe, f1bl, f1sl, f1bl, f1sl, f1bl, f1sl, 1024, 1024, 2304, 256, 768,
        f1p, nullptr, 0);
    expand_ff<<<1024, 256, 0, stream>>>(f1p, Xe2);
    // f2: split-K x8 (512 blocks, 9 iters/slice)
    gemm_kw<64, 64, 128, 2, 0><<<dim3(16, 4, 8), 256, 0, stream>>>(
        Xe2, f2bl, f2sl, f2bl, f2sl, f2bl, f2sl, 256, 256, 9216, 1024, 1152,
        part, nullptr, 0);
    add_ln_x<<<TOKENS / 4, 256, 0, stream>>>(part, 8, TOKENS * 256, xbuf,
                                             l2g + l * 256, l2b + l * 256, 1e-5f, 0, xbuf, Xe);
  }

  // head: KAN -> gelu -> LN(no affine, eps 1e-12) -> KAN to vocab
  gemm_kw<64, 64, 128, 2, 0><<<dim3(16, 4, 9), 256, 0, stream>>>(
      Xe, hkb, hks, hkb, hks, hkb, hks, 256, 256, 2304, 256, 256, part, nullptr, 0);
  add_ln_x<<<TOKENS / 4, 256, 0, stream>>>(part, 9, TOKENS * 256, nullptr, nullptr, nullptr,
                                           1e-12f, 1, tmp, Xe);
  gemm_kw<128, 128, 64, 1, 0><<<dim3(8, 250), 256, 0, stream>>>(
      Xe, hob, hos, hob, hos, hob, hos, 32000, 32000, 2304, 256, 2304, out, nullptr, 0);
}